// Round 2
// baseline (520.198 us; speedup 1.0000x reference)
//
#include <hip/hip_runtime.h>
#include <math.h>

// Problem constants
#define D_ELEMS 25088   // C*H*W = 512*7*7
#define D4      6272    // D_ELEMS / 4
#define D2      12544   // D_ELEMS / 2
#define N_MEM   2000
#define B_KEYS  32
#define PI_2F   1.570795f   // 3.14159 / 2, matches reference
#define EPSF    1e-8f

// ws layout (floats):
//   [0, 64000)          dots[n][b]  (later overwritten in-place with softmax w)
//   [64000, 66000)      m_norm2[n]
//   [66048, +ns*802816) partial[s][b][d]

__global__ __launch_bounds__(256) void k_zero(float* __restrict__ ws) {
    ws[blockIdx.x * 256 + threadIdx.x] = 0.f;   // grid 258*256 == 66048 exactly
}

// dots[n][b] = sum_d key[b][d]*mem[n][d]; m_norm2[n] = sum_d mem[n][d]^2
// grid: 250 n-tiles (NT=8) x 7 d-slices (98 f4-chunks = 7*14) -> 1750 blocks.
// block: 256 thr = 4 waves, wave bg handles keys [bg*8, bg*8+8).
__global__ __launch_bounds__(256) void k_dots(const float* __restrict__ key,
                                              const float* __restrict__ mem,
                                              float* __restrict__ dots,
                                              float* __restrict__ mnorm2) {
    const int nb   = blockIdx.x / 7;     // 0..249
    const int s    = blockIdx.x % 7;     // 0..6
    const int n0   = nb * 8;
    const int bg   = threadIdx.x >> 6;
    const int lane = threadIdx.x & 63;

    const float4* K4 = (const float4*)key;
    const float4* M4 = (const float4*)mem;

    float acc[8][8];   // [n_local][b_local]
#pragma unroll
    for (int j = 0; j < 8; ++j)
#pragma unroll
        for (int i = 0; i < 8; ++i) acc[j][i] = 0.f;
    float msq[8] = {0.f,0.f,0.f,0.f,0.f,0.f,0.f,0.f};

    const int c0 = s * 14;               // 14 chunks of 64 f4 per slice
    for (int c = 0; c < 14; ++c) {
        const int d4 = (c0 + c) * 64 + lane;
        float4 kf[8], mf[8];
#pragma unroll
        for (int i = 0; i < 8; ++i) kf[i] = K4[(bg * 8 + i) * D4 + d4];
#pragma unroll
        for (int j = 0; j < 8; ++j) mf[j] = M4[(n0 + j) * D4 + d4];
#pragma unroll
        for (int j = 0; j < 8; ++j) {
#pragma unroll
            for (int i = 0; i < 8; ++i) {
                acc[j][i] += mf[j].x * kf[i].x + mf[j].y * kf[i].y
                           + mf[j].z * kf[i].z + mf[j].w * kf[i].w;
            }
        }
        if (bg == 0) {
#pragma unroll
            for (int j = 0; j < 8; ++j)
                msq[j] += mf[j].x * mf[j].x + mf[j].y * mf[j].y
                        + mf[j].z * mf[j].z + mf[j].w * mf[j].w;
        }
    }

    // butterfly over lane bits 3..5 -> lanes sharing (lane&7) hold partial sums
#pragma unroll
    for (int off = 8; off < 64; off <<= 1)
#pragma unroll
        for (int j = 0; j < 8; ++j)
#pragma unroll
            for (int i = 0; i < 8; ++i)
                acc[j][i] += __shfl_xor(acc[j][i], off, 64);

    __shared__ float red[4][8][65];
    if (lane < 8) {
#pragma unroll
        for (int j = 0; j < 8; ++j)
#pragma unroll
            for (int i = 0; i < 8; ++i)
                red[bg][lane][j * 8 + i] = acc[j][i];
    }
    __syncthreads();

    // lane j owns (n_local = j>>3, b_local = j&7)
    float ssum = red[bg][0][lane];
#pragma unroll
    for (int i = 1; i < 8; ++i) ssum += red[bg][i][lane];
    atomicAdd(&dots[(n0 + (lane >> 3)) * B_KEYS + bg * 8 + (lane & 7)], ssum);

    if (bg == 0) {
#pragma unroll
        for (int off = 1; off < 64; off <<= 1)
#pragma unroll
            for (int j = 0; j < 8; ++j)
                msq[j] += __shfl_xor(msq[j], off, 64);
        if (lane == 0) {
#pragma unroll
            for (int j = 0; j < 8; ++j) atomicAdd(&mnorm2[n0 + j], msq[j]);
        }
    }
}

// per-b: k_norm, cos -> tan -> softmax over n. Writes w in-place into dots
// column b (each block touches only its own column).
__global__ __launch_bounds__(256) void k_softmax(const float* __restrict__ key,
                                                 const float* __restrict__ dots,
                                                 const float* __restrict__ mnorm2,
                                                 float* __restrict__ w) {
    const int b   = blockIdx.x;
    const int tid = threadIdx.x;
    __shared__ float sred[256];
    __shared__ float xbuf[N_MEM];

    const float4* K4 = (const float4*)(key + (size_t)b * D_ELEMS);
    float ks = 0.f;
    for (int i = tid; i < D4; i += 256) {
        float4 kf = K4[i];
        ks += kf.x * kf.x + kf.y * kf.y + kf.z * kf.z + kf.w * kf.w;
    }
    sred[tid] = ks;
    __syncthreads();
    for (int o = 128; o; o >>= 1) {
        if (tid < o) sred[tid] += sred[tid + o];
        __syncthreads();
    }
    const float knorm = fmaxf(sqrtf(sred[0]), EPSF);
    __syncthreads();

    float mx = -1e30f;
    for (int n = tid; n < N_MEM; n += 256) {
        float mn   = fmaxf(sqrtf(mnorm2[n]), EPSF);
        float cosv = dots[n * B_KEYS + b] / (knorm * mn);
        float x    = tanf(cosv * PI_2F);
        xbuf[n] = x;
        mx = fmaxf(mx, x);
    }
    sred[tid] = mx;
    __syncthreads();
    for (int o = 128; o; o >>= 1) {
        if (tid < o) sred[tid] = fmaxf(sred[tid], sred[tid + o]);
        __syncthreads();
    }
    mx = sred[0];
    __syncthreads();

    float sm = 0.f;
    for (int n = tid; n < N_MEM; n += 256) sm += expf(xbuf[n] - mx);
    sred[tid] = sm;
    __syncthreads();
    for (int o = 128; o; o >>= 1) {
        if (tid < o) sred[tid] += sred[tid + o];
        __syncthreads();
    }
    const float inv = 1.f / sred[0];
    __syncthreads();

    for (int n = tid; n < N_MEM; n += 256)
        w[n * B_KEYS + b] = expf(xbuf[n] - mx) * inv;
}

// partial[s][b][d] = sum_{n in chunk s} w[n][b] * mem[n][d]
// grid: 98 d-blocks x ns n-splits; block 512 thr = 4 b-groups x 128 d-columns.
// Each thread owns one float2 column and 8 b-accumulator pairs. w is read via
// block-uniform float4 global loads (scalarizable to s_load) -- no LDS.
__global__ __launch_bounds__(512) void k_read(const float* __restrict__ mem,
                                              const float* __restrict__ w,
                                              float* __restrict__ partial,
                                              int nPerS) {
    const int db   = blockIdx.x % 98;
    const int s    = blockIdx.x / 98;
    const int n0   = s * nPerS;
    const int bgrp = threadIdx.x >> 7;              // 0..3
    const int b0   = bgrp * 8;
    const int d2   = db * 128 + (threadIdx.x & 127); // float2 column, < 12544

    const float2* M2 = (const float2*)mem;
    const float4* W4 = (const float4*)w;

    float accx[8], accy[8];
#pragma unroll
    for (int i = 0; i < 8; ++i) { accx[i] = 0.f; accy[i] = 0.f; }

    for (int nn = 0; nn < nPerS; ++nn) {
        const int n = n0 + nn;
        const float2 mv = M2[(size_t)n * D2 + d2];
        const float4 wa = W4[n * 8 + bgrp * 2];      // w[n][b0..b0+3]
        const float4 wb = W4[n * 8 + bgrp * 2 + 1];  // w[n][b0+4..b0+7]
        const float wv[8] = {wa.x, wa.y, wa.z, wa.w, wb.x, wb.y, wb.z, wb.w};
#pragma unroll
        for (int i = 0; i < 8; ++i) {
            accx[i] += wv[i] * mv.x;
            accy[i] += wv[i] * mv.y;
        }
    }

    float2* P2 = (float2*)partial;
#pragma unroll
    for (int i = 0; i < 8; ++i)
        P2[(size_t)(s * B_KEYS + b0 + i) * D2 + d2] = make_float2(accx[i], accy[i]);
}

__global__ __launch_bounds__(256) void k_finish(const float* __restrict__ partial,
                                                float* __restrict__ out, int ns) {
    const int i = blockIdx.x * 256 + threadIdx.x;   // grid 3136*256 == 802816
    float sum = 0.f;
    for (int s = 0; s < ns; ++s) sum += partial[(size_t)s * (B_KEYS * D_ELEMS) + i];
    out[i] = sum;
}

extern "C" void kernel_launch(void* const* d_in, const int* in_sizes, int n_in,
                              void* d_out, int out_size, void* d_ws, size_t ws_size,
                              hipStream_t stream) {
    (void)in_sizes; (void)n_in; (void)out_size;
    const float* key = (const float*)d_in[0];
    const float* mem = (const float*)d_in[1];
    float* out = (float*)d_out;
    float* ws  = (float*)d_ws;

    float* dots   = ws;            // 64000 floats
    float* mnorm2 = ws + 64000;    // 2000 floats
    float* part   = ws + 66048;    // ns * 802816 floats

    int ns = 16;   // n-splits for k_read; shrink if ws is small (all divide 2000)
    while (ns > 1 && (size_t)(66048 + (size_t)ns * 802816) * 4 > ws_size) ns >>= 1;
    const int nPerS = N_MEM / ns;

    k_zero   <<<258, 256, 0, stream>>>(ws);
    k_dots   <<<1750, 256, 0, stream>>>(key, mem, dots, mnorm2);
    k_softmax<<<B_KEYS, 256, 0, stream>>>(key, dots, mnorm2, dots);
    k_read   <<<98 * ns, 512, 0, stream>>>(mem, dots, part, nPerS);
    k_finish <<<3136, 256, 0, stream>>>(part, out, ns);
}

// Round 3
// 439.187 us; speedup vs baseline: 1.1845x; 1.1845x over previous
//
#include <hip/hip_runtime.h>
#include <math.h>

// Problem constants
#define D_ELEMS 25088   // C*H*W = 512*7*7
#define D4      6272    // D_ELEMS / 4
#define N_MEM   2000
#define B_KEYS  32
#define PI_2F   1.570795f   // 3.14159 / 2, matches reference
#define EPSF    1e-8f

// ws layout (floats):
//   dots_part [7][2000][32] : [0, 448000)        (per-d-slice partial dots)
//   mn2_part  [7][2000]     : [448000, 462000)   (per-d-slice partial |m|^2)
//   w         [2000][32]    : [462016, 526016)   (16B-aligned)
//   partial [ns][32][25088] : [526080, +ns*802816) (16B-aligned)

// dots_part[s][n][b] = sum_{d in slice s} key[b][d]*mem[n][d]
// grid: 250 n-tiles (NT=8) x 7 d-slices. block 256 = 4 waves; wave bg owns
// keys [bg*8, bg*8+8). No atomics: each block stores its own slice.
__global__ __launch_bounds__(256) void k_dots(const float* __restrict__ key,
                                              const float* __restrict__ mem,
                                              float* __restrict__ dots_part,
                                              float* __restrict__ mn2_part) {
    const int nb   = blockIdx.x / 7;     // 0..249
    const int s    = blockIdx.x % 7;     // 0..6
    const int n0   = nb * 8;
    const int bg   = threadIdx.x >> 6;
    const int lane = threadIdx.x & 63;

    const float4* K4 = (const float4*)key;
    const float4* M4 = (const float4*)mem;

    float acc[8][8];   // [n_local][b_local]
#pragma unroll
    for (int j = 0; j < 8; ++j)
#pragma unroll
        for (int i = 0; i < 8; ++i) acc[j][i] = 0.f;
    float msq[8] = {0.f,0.f,0.f,0.f,0.f,0.f,0.f,0.f};

    const int c0 = s * 14;               // 14 chunks of 64 f4 per slice
    for (int c = 0; c < 14; ++c) {
        const int d4 = (c0 + c) * 64 + lane;
        float4 kf[8], mf[8];
#pragma unroll
        for (int i = 0; i < 8; ++i) kf[i] = K4[(bg * 8 + i) * D4 + d4];
#pragma unroll
        for (int j = 0; j < 8; ++j) mf[j] = M4[(n0 + j) * D4 + d4];
#pragma unroll
        for (int j = 0; j < 8; ++j) {
#pragma unroll
            for (int i = 0; i < 8; ++i) {
                acc[j][i] += mf[j].x * kf[i].x + mf[j].y * kf[i].y
                           + mf[j].z * kf[i].z + mf[j].w * kf[i].w;
            }
        }
        if (bg == 0) {
#pragma unroll
            for (int j = 0; j < 8; ++j)
                msq[j] += mf[j].x * mf[j].x + mf[j].y * mf[j].y
                        + mf[j].z * mf[j].z + mf[j].w * mf[j].w;
        }
    }

    // butterfly over lane bits 3..5 -> lanes sharing (lane&7) hold partials
#pragma unroll
    for (int off = 8; off < 64; off <<= 1)
#pragma unroll
        for (int j = 0; j < 8; ++j)
#pragma unroll
            for (int i = 0; i < 8; ++i)
                acc[j][i] += __shfl_xor(acc[j][i], off, 64);

    __shared__ float red[4][8][65];
    if (lane < 8) {
#pragma unroll
        for (int j = 0; j < 8; ++j)
#pragma unroll
            for (int i = 0; i < 8; ++i)
                red[bg][lane][j * 8 + i] = acc[j][i];
    }
    __syncthreads();

    // lane j owns (n_local = j>>3, b_local = j&7)
    float ssum = red[bg][0][lane];
#pragma unroll
    for (int i = 1; i < 8; ++i) ssum += red[bg][i][lane];
    dots_part[(size_t)(s * N_MEM + n0 + (lane >> 3)) * B_KEYS + bg * 8 + (lane & 7)] = ssum;

    if (bg == 0) {
#pragma unroll
        for (int off = 1; off < 64; off <<= 1)
#pragma unroll
            for (int j = 0; j < 8; ++j)
                msq[j] += __shfl_xor(msq[j], off, 64);
        if (lane == 0) {
#pragma unroll
            for (int j = 0; j < 8; ++j) mn2_part[s * N_MEM + n0 + j] = msq[j];
        }
    }
}

// per-b: k_norm, sum 7 partials -> cos -> tan -> softmax over n -> w.
__global__ __launch_bounds__(512) void k_softmax(const float* __restrict__ key,
                                                 const float* __restrict__ dots_part,
                                                 const float* __restrict__ mn2_part,
                                                 float* __restrict__ w) {
    const int b   = blockIdx.x;
    const int tid = threadIdx.x;
    __shared__ float sred[512];
    __shared__ float xbuf[N_MEM];

    const float4* K4 = (const float4*)(key + (size_t)b * D_ELEMS);
    float ks = 0.f;
    for (int i = tid; i < D4; i += 512) {
        float4 kf = K4[i];
        ks += kf.x * kf.x + kf.y * kf.y + kf.z * kf.z + kf.w * kf.w;
    }
    sred[tid] = ks;
    __syncthreads();
    for (int o = 256; o; o >>= 1) {
        if (tid < o) sred[tid] += sred[tid + o];
        __syncthreads();
    }
    const float knorm = fmaxf(sqrtf(sred[0]), EPSF);
    __syncthreads();

    float mx = -1e30f;
    for (int n = tid; n < N_MEM; n += 512) {
        float ds = 0.f, ms = 0.f;
#pragma unroll
        for (int s = 0; s < 7; ++s) ds += dots_part[(size_t)(s * N_MEM + n) * B_KEYS + b];
#pragma unroll
        for (int s = 0; s < 7; ++s) ms += mn2_part[s * N_MEM + n];
        float mn = fmaxf(sqrtf(ms), EPSF);
        float x  = __tanf((ds / (knorm * mn)) * PI_2F);
        xbuf[n] = x;
        mx = fmaxf(mx, x);
    }
    sred[tid] = mx;
    __syncthreads();
    for (int o = 256; o; o >>= 1) {
        if (tid < o) sred[tid] = fmaxf(sred[tid], sred[tid + o]);
        __syncthreads();
    }
    mx = sred[0];
    __syncthreads();

    float sm = 0.f;
    for (int n = tid; n < N_MEM; n += 512) sm += __expf(xbuf[n] - mx);
    sred[tid] = sm;
    __syncthreads();
    for (int o = 256; o; o >>= 1) {
        if (tid < o) sred[tid] += sred[tid + o];
        __syncthreads();
    }
    const float inv = 1.f / sred[0];
    __syncthreads();

    for (int n = tid; n < N_MEM; n += 512)
        w[n * B_KEYS + b] = __expf(xbuf[n] - mx) * inv;
}

// partial[s][b][d] = sum_{n in split s} w[n][b] * mem[n][d]
// grid: 98 d-blocks x ns splits. block 256 = 4 waves; wave bg owns b-group
// bg*8..bg*8+7; 64 lanes own one float4 d-column (coalesced 1KB/load).
// w staged in LDS once per 250-n chunk, read as wave-uniform float4 pairs.
// Depth-1 prefetch of the mem float4 keeps one load in flight.
__global__ __launch_bounds__(256) void k_read(const float* __restrict__ mem,
                                              const float* __restrict__ w,
                                              float* __restrict__ partial,
                                              int nPerS) {
    const int db   = blockIdx.x % 98;
    const int s    = blockIdx.x / 98;
    const int n0   = s * nPerS;
    const int bg   = threadIdx.x >> 6;          // 0..3, b0 = bg*8
    const int lane = threadIdx.x & 63;
    const int d4   = db * 64 + lane;            // float4 column, < 6272

    const float4* M4 = (const float4*)mem;
    const float4* W4 = (const float4*)w;
    __shared__ float4 wls4[250 * 8];            // 250 n x 32 b = 32 KB

    float acc[8][4];
#pragma unroll
    for (int i = 0; i < 8; ++i)
#pragma unroll
        for (int j = 0; j < 4; ++j) acc[i][j] = 0.f;

    for (int c0 = 0; c0 < nPerS; c0 += 250) {
        const int cn = min(250, nPerS - c0);
        __syncthreads();
        for (int i = threadIdx.x; i < cn * 8; i += 256)
            wls4[i] = W4[(n0 + c0) * 8 + i];
        __syncthreads();

        float4 mv = M4[(size_t)(n0 + c0) * D4 + d4];
        float4 wa = wls4[bg * 2];
        float4 wb = wls4[bg * 2 + 1];
        for (int nn = 0; nn < cn; ++nn) {
            const float4 mc = mv, wac = wa, wbc = wb;
            const int nx = (nn + 1 < cn) ? nn + 1 : nn;
            mv = M4[(size_t)(n0 + c0 + nx) * D4 + d4];
            wa = wls4[nx * 8 + bg * 2];
            wb = wls4[nx * 8 + bg * 2 + 1];
            const float wv[8] = {wac.x, wac.y, wac.z, wac.w,
                                 wbc.x, wbc.y, wbc.z, wbc.w};
#pragma unroll
            for (int i = 0; i < 8; ++i) {
                acc[i][0] += wv[i] * mc.x;
                acc[i][1] += wv[i] * mc.y;
                acc[i][2] += wv[i] * mc.z;
                acc[i][3] += wv[i] * mc.w;
            }
        }
    }

    float4* P4 = (float4*)partial;
#pragma unroll
    for (int i = 0; i < 8; ++i)
        P4[(size_t)(s * B_KEYS + bg * 8 + i) * D4 + d4] =
            make_float4(acc[i][0], acc[i][1], acc[i][2], acc[i][3]);
}

__global__ __launch_bounds__(256) void k_finish(const float* __restrict__ partial,
                                                float* __restrict__ out, int ns) {
    const int i = blockIdx.x * 256 + threadIdx.x;   // float4 index, grid 784*256
    const float4* P4 = (const float4*)partial;
    float4 sum = P4[i];
    for (int s = 1; s < ns; ++s) {
        const float4 p = P4[(size_t)s * (B_KEYS * D4) + i];
        sum.x += p.x; sum.y += p.y; sum.z += p.z; sum.w += p.w;
    }
    ((float4*)out)[i] = sum;
}

extern "C" void kernel_launch(void* const* d_in, const int* in_sizes, int n_in,
                              void* d_out, int out_size, void* d_ws, size_t ws_size,
                              hipStream_t stream) {
    (void)in_sizes; (void)n_in; (void)out_size;
    const float* key = (const float*)d_in[0];
    const float* mem = (const float*)d_in[1];
    float* out = (float*)d_out;
    float* ws  = (float*)d_ws;

    float* dots_part = ws;              // 448000 floats
    float* mn2_part  = ws + 448000;     // 14000 floats
    float* w         = ws + 462016;     // 64000 floats (16B aligned)
    float* part      = ws + 526080;     // ns * 802816 floats (16B aligned)

    int ns = 8;   // n-splits for k_read (all candidates divide 2000)
    while (ns > 1 && (size_t)(526080 + (size_t)ns * 802816) * 4 > ws_size) ns >>= 1;
    const int nPerS = N_MEM / ns;

    k_dots   <<<1750, 256, 0, stream>>>(key, mem, dots_part, mn2_part);
    k_softmax<<<B_KEYS, 512, 0, stream>>>(key, dots_part, mn2_part, w);
    k_read   <<<98 * ns, 256, 0, stream>>>(mem, w, part, nPerS);
    k_finish <<<784, 256, 0, stream>>>(part, out, ns);
}

// Round 4
// 420.318 us; speedup vs baseline: 1.2376x; 1.0449x over previous
//
#include <hip/hip_runtime.h>
#include <math.h>

// Problem constants
#define D_ELEMS 25088   // C*H*W = 512*7*7
#define D4      6272    // D_ELEMS / 4
#define N_MEM   2000
#define B_KEYS  32
#define PI_2F   1.570795f   // 3.14159 / 2, matches reference
#define EPSF    1e-8f
#define NSLICE  8           // k-slices for k_dots_mfma
#define KSLICE  3136        // 25088 / 8
#define KSTEPS  98          // KSLICE / 32

using short8 = __attribute__((ext_vector_type(8))) short;   // 8 bf16 A/B frag
using short4v = __attribute__((ext_vector_type(4))) short;
using f32x4  = __attribute__((ext_vector_type(4))) float;   // C/D frag

// ws layout (floats):
//   keyb (bf16 keys, as shorts)   : [0, 401408)
//   dots_part [8][2000][32]       : [401408, 913408)
//   mn2_part  [8][2000]           : [913408, 929408)
//   w         [2000][32]          : [929408, 993408)
//   partial [ns][32][25088]       : [993408, +ns*802816)

__device__ inline short f2bf(float x) {   // fp32 -> bf16 RNE (inputs finite)
    union { float f; unsigned u; } v; v.f = x;
    unsigned r = v.u + 0x7fffu + ((v.u >> 16) & 1u);
    return (short)(r >> 16);
}

// Convert keys fp32 -> bf16 once. 802816 elems, 4 per thread.
__global__ __launch_bounds__(256) void k_prep(const float* __restrict__ key,
                                              short* __restrict__ keyb) {
    const int i = blockIdx.x * 256 + threadIdx.x;   // float4 index, grid 784*256
    const float4 f = ((const float4*)key)[i];
    short4v s; s[0] = f2bf(f.x); s[1] = f2bf(f.y); s[2] = f2bf(f.z); s[3] = f2bf(f.w);
    ((short4v*)keyb)[i] = s;
}

// dots_part[s][n][b] = sum_{k in slice s} key[b][k]*mem[n][k]  (bf16 MFMA)
// mn2_part[s][n]     = sum_{k in slice s} mem[n][k]^2          (fp32)
// grid: 125 n-tiles x 8 slices = 1000 blocks of 1 wave (64 thr).
// Per k-step: 2 A frag loads (bf16 keys), 2 float4 mem loads (-> cvt to B
// frag), 2 mfma into the two 16-row halves of the 32-key dimension.
__global__ __launch_bounds__(64) void k_dots_mfma(const short* __restrict__ keyb,
                                                  const float* __restrict__ mem,
                                                  float* __restrict__ dots_part,
                                                  float* __restrict__ mn2_part) {
    const int nt   = blockIdx.x / NSLICE;     // 0..124
    const int s    = blockIdx.x % NSLICE;     // 0..7
    const int n0   = nt * 16;
    const int lane = threadIdx.x;             // 0..63
    const int quad = lane >> 4;
    const int l16  = lane & 15;
    const int k0   = s * KSLICE + quad * 8;   // this lane's k base (floats)

    const short* a0p = keyb + (size_t)l16 * D_ELEMS + k0;          // keys 0..15
    const short* a1p = keyb + (size_t)(16 + l16) * D_ELEMS + k0;   // keys 16..31
    const float4* bp = (const float4*)(mem + (size_t)(n0 + l16) * D_ELEMS + k0);

    f32x4 acc0 = {0.f, 0.f, 0.f, 0.f};
    f32x4 acc1 = {0.f, 0.f, 0.f, 0.f};
    float msq = 0.f;

    // depth-1 prefetch: loads for step t+1 issue before the cvt+mfma of t
    short8 a0 = *(const short8*)a0p;
    short8 a1 = *(const short8*)a1p;
    float4 f0 = bp[0], f1 = bp[1];

    for (int t = 0; t < KSTEPS; ++t) {
        const short8 a0c = a0, a1c = a1;
        const float4 f0c = f0, f1c = f1;
        if (t + 1 < KSTEPS) {
            const int ko = (t + 1) * 8;       // float4 index advance (32 floats)
            a0 = *(const short8*)(a0p + (t + 1) * 32);
            a1 = *(const short8*)(a1p + (t + 1) * 32);
            f0 = bp[ko]; f1 = bp[ko + 1];
        }
        msq += f0c.x * f0c.x + f0c.y * f0c.y + f0c.z * f0c.z + f0c.w * f0c.w
             + f1c.x * f1c.x + f1c.y * f1c.y + f1c.z * f1c.z + f1c.w * f1c.w;
        short8 b;
        b[0] = f2bf(f0c.x); b[1] = f2bf(f0c.y); b[2] = f2bf(f0c.z); b[3] = f2bf(f0c.w);
        b[4] = f2bf(f1c.x); b[5] = f2bf(f1c.y); b[6] = f2bf(f1c.z); b[7] = f2bf(f1c.w);
        acc0 = __builtin_amdgcn_mfma_f32_16x16x32_bf16(a0c, b, acc0, 0, 0, 0);
        acc1 = __builtin_amdgcn_mfma_f32_16x16x32_bf16(a1c, b, acc1, 0, 0, 0);
    }

    // D[row=quad*4+r][col=l16]; row = key index (per m-half), col = n index
    float* dp = dots_part + (size_t)(s * N_MEM + n0 + l16) * B_KEYS;
#pragma unroll
    for (int r = 0; r < 4; ++r) {
        dp[quad * 4 + r]      = acc0[r];
        dp[16 + quad * 4 + r] = acc1[r];
    }

    // reduce msq across the 4 quads of each n-row (lanes l16, l16+16, ...)
    msq += __shfl_xor(msq, 16, 64);
    msq += __shfl_xor(msq, 32, 64);
    if (lane < 16) mn2_part[s * N_MEM + n0 + lane] = msq;
}

// per-b: k_norm (fp32 keys), sum 8 slice partials -> cos -> tan -> softmax.
__global__ __launch_bounds__(512) void k_softmax(const float* __restrict__ key,
                                                 const float* __restrict__ dots_part,
                                                 const float* __restrict__ mn2_part,
                                                 float* __restrict__ w) {
    const int b   = blockIdx.x;
    const int tid = threadIdx.x;
    __shared__ float sred[512];
    __shared__ float xbuf[N_MEM];

    const float4* K4 = (const float4*)(key + (size_t)b * D_ELEMS);
    float ks = 0.f;
    for (int i = tid; i < D4; i += 512) {
        float4 kf = K4[i];
        ks += kf.x * kf.x + kf.y * kf.y + kf.z * kf.z + kf.w * kf.w;
    }
    sred[tid] = ks;
    __syncthreads();
    for (int o = 256; o; o >>= 1) {
        if (tid < o) sred[tid] += sred[tid + o];
        __syncthreads();
    }
    const float knorm = fmaxf(sqrtf(sred[0]), EPSF);
    __syncthreads();

    float mx = -1e30f;
    for (int n = tid; n < N_MEM; n += 512) {
        float ds = 0.f, ms = 0.f;
#pragma unroll
        for (int s = 0; s < NSLICE; ++s) ds += dots_part[(size_t)(s * N_MEM + n) * B_KEYS + b];
#pragma unroll
        for (int s = 0; s < NSLICE; ++s) ms += mn2_part[s * N_MEM + n];
        float mn = fmaxf(sqrtf(ms), EPSF);
        float x  = __tanf((ds / (knorm * mn)) * PI_2F);
        xbuf[n] = x;
        mx = fmaxf(mx, x);
    }
    sred[tid] = mx;
    __syncthreads();
    for (int o = 256; o; o >>= 1) {
        if (tid < o) sred[tid] = fmaxf(sred[tid], sred[tid + o]);
        __syncthreads();
    }
    mx = sred[0];
    __syncthreads();

    float sm = 0.f;
    for (int n = tid; n < N_MEM; n += 512) sm += __expf(xbuf[n] - mx);
    sred[tid] = sm;
    __syncthreads();
    for (int o = 256; o; o >>= 1) {
        if (tid < o) sred[tid] += sred[tid + o];
        __syncthreads();
    }
    const float inv = 1.f / sred[0];
    __syncthreads();

    for (int n = tid; n < N_MEM; n += 512)
        w[n * B_KEYS + b] = __expf(xbuf[n] - mx) * inv;
}

// partial[s][b][d] = sum_{n in split s} w[n][b] * mem[n][d]
// (unchanged from R2 -- the 187->~110us version)
__global__ __launch_bounds__(256) void k_read(const float* __restrict__ mem,
                                              const float* __restrict__ w,
                                              float* __restrict__ partial,
                                              int nPerS) {
    const int db   = blockIdx.x % 98;
    const int s    = blockIdx.x / 98;
    const int n0   = s * nPerS;
    const int bg   = threadIdx.x >> 6;          // 0..3, b0 = bg*8
    const int lane = threadIdx.x & 63;
    const int d4   = db * 64 + lane;            // float4 column, < 6272

    const float4* M4 = (const float4*)mem;
    const float4* W4 = (const float4*)w;
    __shared__ float4 wls4[250 * 8];            // 250 n x 32 b = 32 KB

    float acc[8][4];
#pragma unroll
    for (int i = 0; i < 8; ++i)
#pragma unroll
        for (int j = 0; j < 4; ++j) acc[i][j] = 0.f;

    for (int c0 = 0; c0 < nPerS; c0 += 250) {
        const int cn = min(250, nPerS - c0);
        __syncthreads();
        for (int i = threadIdx.x; i < cn * 8; i += 256)
            wls4[i] = W4[(n0 + c0) * 8 + i];
        __syncthreads();

        float4 mv = M4[(size_t)(n0 + c0) * D4 + d4];
        float4 wa = wls4[bg * 2];
        float4 wb = wls4[bg * 2 + 1];
        for (int nn = 0; nn < cn; ++nn) {
            const float4 mc = mv, wac = wa, wbc = wb;
            const int nx = (nn + 1 < cn) ? nn + 1 : nn;
            mv = M4[(size_t)(n0 + c0 + nx) * D4 + d4];
            wa = wls4[nx * 8 + bg * 2];
            wb = wls4[nx * 8 + bg * 2 + 1];
            const float wv[8] = {wac.x, wac.y, wac.z, wac.w,
                                 wbc.x, wbc.y, wbc.z, wbc.w};
#pragma unroll
            for (int i = 0; i < 8; ++i) {
                acc[i][0] += wv[i] * mc.x;
                acc[i][1] += wv[i] * mc.y;
                acc[i][2] += wv[i] * mc.z;
                acc[i][3] += wv[i] * mc.w;
            }
        }
    }

    float4* P4 = (float4*)partial;
#pragma unroll
    for (int i = 0; i < 8; ++i)
        P4[(size_t)(s * B_KEYS + bg * 8 + i) * D4 + d4] =
            make_float4(acc[i][0], acc[i][1], acc[i][2], acc[i][3]);
}

__global__ __launch_bounds__(256) void k_finish(const float* __restrict__ partial,
                                                float* __restrict__ out, int ns) {
    const int i = blockIdx.x * 256 + threadIdx.x;   // float4 index, grid 784*256
    const float4* P4 = (const float4*)partial;
    float4 sum = P4[i];
    for (int s = 1; s < ns; ++s) {
        const float4 p = P4[(size_t)s * (B_KEYS * D4) + i];
        sum.x += p.x; sum.y += p.y; sum.z += p.z; sum.w += p.w;
    }
    ((float4*)out)[i] = sum;
}

extern "C" void kernel_launch(void* const* d_in, const int* in_sizes, int n_in,
                              void* d_out, int out_size, void* d_ws, size_t ws_size,
                              hipStream_t stream) {
    (void)in_sizes; (void)n_in; (void)out_size;
    const float* key = (const float*)d_in[0];
    const float* mem = (const float*)d_in[1];
    float* out = (float*)d_out;
    float* ws  = (float*)d_ws;

    short* keyb      = (short*)ws;      // 802816 shorts = 401408 floats
    float* dots_part = ws + 401408;     // 512000 floats
    float* mn2_part  = ws + 913408;     // 16000 floats
    float* w         = ws + 929408;     // 64000 floats (16B aligned)
    float* part      = ws + 993408;     // ns * 802816 floats (16B aligned)

    int ns = 8;   // n-splits for k_read (all candidates divide 2000)
    while (ns > 1 && (size_t)(993408 + (size_t)ns * 802816) * 4 > ws_size) ns >>= 1;
    const int nPerS = N_MEM / ns;

    k_prep     <<<784, 256, 0, stream>>>(key, keyb);
    k_dots_mfma<<<125 * NSLICE, 64, 0, stream>>>(keyb, mem, dots_part, mn2_part);
    k_softmax  <<<B_KEYS, 512, 0, stream>>>(key, dots_part, mn2_part, w);
    k_read     <<<98 * ns, 256, 0, stream>>>(mem, w, part, nPerS);
    k_finish   <<<784, 256, 0, stream>>>(part, out, ns);
}